// Round 4
// baseline (447.503 us; speedup 1.0000x reference)
//
#include <hip/hip_runtime.h>

// 3x3 median pool, stride 1, zero-pad 1, (8,32,512,512) fp32.
//
// Full-row wave, aligned-only VMEM, minimal-shfl rolling ring.
//
// One wave owns a full 512-wide x 32-row strip. Lane i owns 8 contiguous
// columns x0 = 8*i .. 8*i+7:
//   A = dwordx4 @ x0      (32B-aligned)
//   B = dwordx4 @ x0+4    (16B-aligned)
// -> 2 aligned loads + 2 aligned stores per row per lane, nothing split at
// the TA (round-3 kernel's dwordx4 @ x0-1 split every read transaction).
// Neighbor columns (x0-1, x0+8) come from 2 raw-value shfls per LOADED row,
// ring-stored so each is computed once per input row, one iteration after
// its load (no same-iteration vmcnt drain). Image-edge columns are fixed
// with 2 lane-constant cndmasks: no divergent loads anywhere, no wave-edge
// halos in x at all (wave spans the whole row).
//
// Ring depth 4, all slot indices compile-time after the 4x inner unroll.
// Iter r: load input row r+2, shfl row r+1 (loaded last iter), compute
// output row r from ring rows r-1, r, r+1.
//
// Grid: 256 planes x 16 strips = 4096 waves = 1024 blocks x 4 waves
//     = exactly 4 blocks/CU, one generation, no tail. The 4 waves of a
// block are 4 vertically-adjacent strips (overlap rows CU-local).
// Read amplification 35/32 = 1.09x.

typedef float f32x4 __attribute__((ext_vector_type(4)));

#define S2(a, b) { float _t = fminf(a, b); b = fmaxf(a, b); a = _t; }

__device__ __forceinline__ float med3f(float a, float b, float c) {
    return fmaxf(fminf(a, b), fminf(fmaxf(a, b), c));
}
__device__ __forceinline__ float max3f(float a, float b, float c) {
    return fmaxf(fmaxf(a, b), c);
}
__device__ __forceinline__ float min3f(float a, float b, float c) {
    return fminf(fminf(a, b), c);
}

__global__ __launch_bounds__(256, 4) void median_pool3x3_kernel(
        const float* __restrict__ in, float* __restrict__ out) {
    constexpr int W = 512, H = 512;
    constexpr int RPW = 32;                // output rows per wave

    const int lane = threadIdx.x & 63;
    const int wib  = threadIdx.x >> 6;
    const int gw   = blockIdx.x * 4 + wib;

    // gw -> { img (256), strip (16) }; block = 4 vertically-adjacent strips.
    const int strip = gw & 15;
    const int img   = gw >> 4;

    const int y0 = strip * RPW;
    const int x0 = lane * 8;

    const float* __restrict__ base  = in  + (size_t)img * H * W;
    float* __restrict__       obase = out + (size_t)img * H * W;
    const float* __restrict__ pin   = base + x0;

    const bool lane0  = (lane == 0);
    const bool lane63 = (lane == 63);

    // Ring: input row k (k = y - y0, from -1) lives in slot (k+1)&3.
    f32x4 ra[4], rb[4];
    float nl[4], nr[4];

    auto loadrow = [&](int y, int s) {
        const float* row = pin + (size_t)y * W;
        ra[s] = *(const f32x4*)row;
        rb[s] = *(const f32x4*)(row + 4);
    };
    auto zerorow = [&](int s) {
        ra[s] = f32x4{0.0f, 0.0f, 0.0f, 0.0f};
        rb[s] = f32x4{0.0f, 0.0f, 0.0f, 0.0f};
    };
    // Neighbor exchange for slot s: col x0-1 (left lane's B.w), col x0+8
    // (right lane's A.x). Image edges are zero-pad.
    auto shflrow = [&](int s) {
        float l = __shfl_up(rb[s].w, 1);
        float r_ = __shfl_down(ra[s].x, 1);
        nl[s] = lane0  ? 0.0f : l;
        nr[s] = lane63 ? 0.0f : r_;
    };

    // ---- prologue: rows y0-1, y0, y0+1 -> slots 0,1,2 (+ shfl slots 0,1) --
    if (y0 > 0) {                          // wave-uniform
        loadrow(y0 - 1, 0);
    } else {
        zerorow(0);
    }
    loadrow(y0,     1);
    loadrow(y0 + 1, 2);
    shflrow(0);
    shflrow(1);

    // 10-column window per lane: [nl, A.xyzw, B.xyzw, nr]
    auto col = [&](int s, int j) -> float {
        switch (j) {
            case 0: return nl[s];
            case 1: return ra[s].x; case 2: return ra[s].y;
            case 3: return ra[s].z; case 4: return ra[s].w;
            case 5: return rb[s].x; case 6: return rb[s].y;
            case 7: return rb[s].z; case 8: return rb[s].w;
            default: return nr[s];
        }
    };

    auto crow = [&](int s0, int s1, int s2, int y) {
        float lo[10], mi[10], hi[10];
        #pragma unroll
        for (int j = 0; j < 10; ++j) {
            float a = col(s0, j), b = col(s1, j), c = col(s2, j);
            S2(a, b); S2(b, c); S2(a, b);
            lo[j] = a; mi[j] = b; hi[j] = c;
        }
        float o[8];
        #pragma unroll
        for (int j = 0; j < 8; ++j) {
            o[j] = med3f(max3f(lo[j], lo[j + 1], lo[j + 2]),
                         med3f(mi[j], mi[j + 1], mi[j + 2]),
                         min3f(hi[j], hi[j + 1], hi[j + 2]));
        }
        float* orow = obase + (size_t)y * W + x0;
        *(f32x4*)orow       = f32x4{o[0], o[1], o[2], o[3]};
        *(f32x4*)(orow + 4) = f32x4{o[4], o[5], o[6], o[7]};
    };

    // ---- main loop: iter r loads row r+2, shfls row r+1, computes row r --
    #pragma unroll 1
    for (int rbase = 0; rbase < RPW; rbase += 4) {
        #pragma unroll
        for (int q = 0; q < 4; ++q) {
            const int r  = rbase + q;
            const int yl = y0 + r + 2;                 // row to load
            const int sl = (r + 3) & 3;
            loadrow(yl < H ? yl : (H - 1), sl);        // unconditional issue
            if (yl >= H) zerorow(sl);                  // wave-uniform (strip 15)
            shflrow((r + 2) & 3);                      // row r+1, loaded last iter
            crow(r & 3, (r + 1) & 3, (r + 2) & 3, y0 + r);
        }
    }
}

extern "C" void kernel_launch(void* const* d_in, const int* in_sizes, int n_in,
                              void* d_out, int out_size, void* d_ws, size_t ws_size,
                              hipStream_t stream) {
    const float* x = (const float*)d_in[0];
    float* out = (float*)d_out;

    // 256 planes x 16 strips = 4096 waves / 4 per block = 1024 blocks
    median_pool3x3_kernel<<<1024, 256, 0, stream>>>(x, out);
}